// Round 20
// baseline (350.487 us; speedup 1.0000x reference)
//
#include <hip/hip_runtime.h>
#include <hip/hip_bf16.h>
#include <hip/hip_fp16.h>
#include <math.h>

#define NN 50000
#define NP 50048            // NN padded to 16-row tiles
#define NE 800000
#define ET (NE + NN)
#define DF 128
#define NH 4
#define HD 512
#define BN_EPS 1e-5f
#define GB (NP / 16)        // 3128 blocks for agg_gemm

typedef __hip_bfloat16 bf16;
typedef __attribute__((ext_vector_type(8))) short bf16x8;
typedef __attribute__((ext_vector_type(4))) float f32x4;
typedef __attribute__((ext_vector_type(2))) float f32x2;

// ---------- input conversions ----------
__global__ __launch_bounds__(256) void cvt_x_bf16(const float* __restrict__ in, bf16* __restrict__ out) {
    int i = blockIdx.x * 256 + threadIdx.x;            // 4 elements per thread
    if (i >= NN * DF / 4) return;
    float4 v = reinterpret_cast<const float4*>(in)[i];
    union { bf16 b[4]; short4 s; } u;
    u.b[0] = __float2bfloat16(v.x); u.b[1] = __float2bfloat16(v.y);
    u.b[2] = __float2bfloat16(v.z); u.b[3] = __float2bfloat16(v.w);
    reinterpret_cast<short4*>(out)[i] = u.s;
}

// wsd[layer][o][d] = sum_c W[d, h*128+c] * att[h][c],  o=h (src, 0..3) or 4+h (dst)
__global__ __launch_bounds__(256) void make_wsd(const float* __restrict__ W1, const float* __restrict__ as1,
                                                const float* __restrict__ ad1,
                                                const float* __restrict__ W2, const float* __restrict__ as2,
                                                const float* __restrict__ ad2,
                                                float* __restrict__ wsd) {
    int t = blockIdx.x * 256 + threadIdx.x;   // 0..2047
    if (t >= 2048) return;
    int layer = t >> 10;
    int o = (t >> 7) & 7;
    int d = t & 127;
    int h = o & 3;
    const float* W  = layer ? W2 : W1;
    const float* av = layer ? (o < 4 ? as2 : ad2) : (o < 4 ? as1 : ad1);
    const float* wrow = W + d * HD + h * DF;
    const float* arow = av + h * DF;
    float sum = 0.f;
    for (int c = 0; c < DF; ++c) sum += wrow[c] * arow[c];
    wsd[layer * 1024 + o * DF + d] = sum;
}

// Bt2[layer][c][h*128+d] = 0.25 * W[d][h*128+c]   (stacked, transposed, head-mean folded)
__global__ __launch_bounds__(256) void cvt_bt2(const float* __restrict__ W1, const float* __restrict__ W2,
                                               bf16* __restrict__ B1, bf16* __restrict__ B2) {
    int i = blockIdx.x * 256 + threadIdx.x;   // 0..131071
    if (i >= 2 * DF * HD) return;
    int layer = i >> 16;
    int ii = i & 65535;
    int c = ii >> 9, k = ii & 511;
    int h = k >> 7, d = k & 127;
    const float* W = layer ? W2 : W1;
    bf16* B = layer ? B2 : B1;
    B[ii] = __float2bfloat16(0.25f * W[d * HD + h * DF + c]);
}

// ---------- per-node scores from x ----------
__global__ __launch_bounds__(256) void xscore(const bf16* __restrict__ X,
                                              const float* __restrict__ wsd,   // [8][128]
                                              float* __restrict__ a_src,
                                              float* __restrict__ a_dst) {
    __shared__ float w[8][DF];
    reinterpret_cast<float4*>(&w[0][0])[threadIdx.x] = reinterpret_cast<const float4*>(wsd)[threadIdx.x];
    __syncthreads();
    const int n = blockIdx.x * 4 + (threadIdx.x >> 6);
    const int l = threadIdx.x & 63;          // lane owns features 2l, 2l+1
    unsigned xv = reinterpret_cast<const unsigned*>(X)[n * 64 + l];
    float x0 = __uint_as_float(xv << 16);
    float x1 = __uint_as_float(xv & 0xffff0000u);
    float v[8];
    #pragma unroll
    for (int o = 0; o < 8; ++o)
        v[o] = x0 * w[o][2 * l] + x1 * w[o][2 * l + 1];
    #pragma unroll
    for (int off = 1; off < 64; off <<= 1) {
        #pragma unroll
        for (int o = 0; o < 8; ++o) v[o] += __shfl_xor(v[o], off);
    }
    if (l == 0) {
        reinterpret_cast<float4*>(a_src)[n] = make_float4(v[0], v[1], v[2], v[3]);
        reinterpret_cast<float4*>(a_dst)[n] = make_float4(v[4], v[5], v[6], v[7]);
    }
}

// ---------- CSR build: single atomic pass (rank trick) ----------
__global__ __launch_bounds__(256) void count_rank(const int* __restrict__ ei, int* __restrict__ counts,
                                                  int* __restrict__ rank) {
    int e = (blockIdx.x * 256 + threadIdx.x) * 2;
    if (e >= ET) return;
    int d0, d1;
    if (e + 1 < NE) {
        int2 dd = *reinterpret_cast<const int2*>(ei + NE + e);
        d0 = dd.x; d1 = dd.y;
    } else {
        d0 = (e < NE) ? ei[NE + e] : (e - NE);
        d1 = (e + 1 < NE) ? ei[NE + e + 1] : (e + 1 - NE);
    }
    rank[e]     = atomicAdd(&counts[d0 << 4], 1);
    rank[e + 1] = atomicAdd(&counts[d1 << 4], 1);
}

__global__ __launch_bounds__(256) void scan1(const int* __restrict__ counts, int* __restrict__ bsum) {
    __shared__ int sd[256];
    int i = blockIdx.x * 256 + threadIdx.x;
    sd[threadIdx.x] = (i < NN) ? counts[i << 4] : 0;
    __syncthreads();
    for (int s = 128; s > 0; s >>= 1) {
        if (threadIdx.x < s) sd[threadIdx.x] += sd[threadIdx.x + s];
        __syncthreads();
    }
    if (threadIdx.x == 0) bsum[blockIdx.x] = sd[0];
}

// parallel exclusive scan over <=256 block sums (Hillis-Steele)
__global__ __launch_bounds__(256) void scan2(int* __restrict__ bsum, int nb) {
    __shared__ int sd[256];
    int i = threadIdx.x;
    int v = (i < nb) ? bsum[i] : 0;
    sd[i] = v;
    __syncthreads();
    for (int s = 1; s < 256; s <<= 1) {
        int t = sd[i];
        int u = (i >= s) ? sd[i - s] : 0;
        __syncthreads();
        sd[i] = t + u;
        __syncthreads();
    }
    if (i < nb) bsum[i] = sd[i] - v;
}

__global__ __launch_bounds__(256) void scan3(const int* __restrict__ counts, const int* __restrict__ bsum,
                                             int* __restrict__ row_ptr) {
    __shared__ int sd[256];
    int i = blockIdx.x * 256 + threadIdx.x;
    int v = (i < NN) ? counts[i << 4] : 0;
    sd[threadIdx.x] = v;
    __syncthreads();
    for (int s = 1; s < 256; s <<= 1) {
        int t = sd[threadIdx.x];
        int u = (threadIdx.x >= s) ? sd[threadIdx.x - s] : 0;
        __syncthreads();
        sd[threadIdx.x] = t + u;
        __syncthreads();
    }
    int excl = sd[threadIdx.x] - v + bsum[blockIdx.x];
    if (i < NN) row_ptr[i] = excl;
    if (i == 0) row_ptr[NN] = ET;
}

// non-atomic scatter: col[row_ptr[d] + rank[e]] = src(e)
__global__ __launch_bounds__(256) void fill_scatter(const int* __restrict__ ei, const int* __restrict__ rank,
                                                    const int* __restrict__ row_ptr, int* __restrict__ col) {
    int e = (blockIdx.x * 256 + threadIdx.x) * 2;
    if (e >= ET) return;
    int s0, d0, s1, d1;
    if (e + 1 < NE) {
        int2 ss = *reinterpret_cast<const int2*>(ei + e);
        int2 dd = *reinterpret_cast<const int2*>(ei + NE + e);
        s0 = ss.x; s1 = ss.y; d0 = dd.x; d1 = dd.y;
    } else {
        if (e < NE) { s0 = ei[e]; d0 = ei[NE + e]; } else { s0 = d0 = e - NE; }
        if (e + 1 < NE) { s1 = ei[e + 1]; d1 = ei[NE + e + 1]; } else { s1 = d1 = e + 1 - NE; }
    }
    int2 rk = *reinterpret_cast<const int2*>(rank + e);
    col[row_ptr[d0] + rk.x] = s0;
    col[row_ptr[d1] + rk.y] = s1;
}

// ---------- fused alpha + gather + output GEMM ----------
// Block = 16 nodes. Phase A/B (per wave, 4 nodes serially): R19's proven bodies,
// agg row written to swizzled LDS A-tile (bf16, same rounding). Then one barrier,
// 16x128 MFMA tile with K=512 (A from LDS, B streamed from L2), BN partials to scratch.
#define EDGEF(xu, pa) {                                                              \
    f32x2 xv;                                                                        \
    xv.x = __uint_as_float((xu) << 16);                                              \
    xv.y = __uint_as_float((xu) & 0xffff0000u);                                      \
    acc2[0] += (pa).x * xv;                                                          \
    acc2[1] += (pa).y * xv;                                                          \
    acc2[2] += (pa).z * xv;                                                          \
    acc2[3] += (pa).w * xv; }

#define EDGE(xu, r) {                                                                \
    f32x2 xv;                                                                        \
    xv.x = __uint_as_float((xu) << 16);                                              \
    xv.y = __uint_as_float((xu) & 0xffff0000u);                                      \
    float2 f01 = __half22float2(*reinterpret_cast<const __half2*>(&(r).x));          \
    float2 f23 = __half22float2(*reinterpret_cast<const __half2*>(&(r).y));          \
    acc2[0] += f01.x * xv;                                                           \
    acc2[1] += f01.y * xv;                                                           \
    acc2[2] += f23.x * xv;                                                           \
    acc2[3] += f23.y * xv; }

__global__ __launch_bounds__(256) void agg_gemm(const bf16* __restrict__ X,
                                                const float* __restrict__ a_src,
                                                const float* __restrict__ a_dst,
                                                const int* __restrict__ row_ptr,
                                                const int* __restrict__ col,
                                                uint4* __restrict__ rec,
                                                const bf16* __restrict__ Bt,
                                                const float* __restrict__ bias,
                                                bf16* __restrict__ outb,
                                                float* __restrict__ scratch, int M) {
    __shared__ __align__(16) char As[16384];       // [16 rows][1024B], XOR-swizzled
    __shared__ __align__(16) float4 lalpha[4][64];
    __shared__ unsigned lcol[4][64];
    const int w = threadIdx.x >> 6;
    const int l = threadIdx.x & 63;
    const unsigned l4 = (unsigned)l << 2;          // byte offset within 256B row
    const int m0 = blockIdx.x * 16;
    const float4* __restrict__ as4 = reinterpret_cast<const float4*>(a_src);
    const char* __restrict__ Xb = reinterpret_cast<const char*>(X);
    // ================= phase A+B: 4 nodes per wave =================
    for (int nn = 0; nn < 4; ++nn) {
        const int r = w * 4 + nn;                  // local row
        const int n = m0 + r;
        char* rowp = As + r * 1024;
        const unsigned swz = (unsigned)((r & 7) << 4);
        f32x2 acc2[4] = {};
        if (n < NN) {
            const int start = row_ptr[n], end = row_ptr[n + 1];
            const int deg = end - start;
            const float4 ad4 = reinterpret_cast<const float4*>(a_dst)[n];
            if (deg <= 64) {
                const int j = start + l;
                int cj = 0;
                float lv[4] = {-1e30f, -1e30f, -1e30f, -1e30f};
                if (j < end) {
                    cj = col[j];
                    float4 a = as4[cj];
                    lv[0] = a.x + ad4.x; lv[1] = a.y + ad4.y; lv[2] = a.z + ad4.z; lv[3] = a.w + ad4.w;
                    #pragma unroll
                    for (int h = 0; h < 4; ++h) lv[h] = lv[h] > 0.f ? lv[h] : 0.2f * lv[h];
                }
                float m[4], p[4], s[4];
                #pragma unroll
                for (int h = 0; h < 4; ++h) m[h] = lv[h];
                #pragma unroll
                for (int off = 1; off < 64; off <<= 1) {
                    #pragma unroll
                    for (int h = 0; h < 4; ++h) m[h] = fmaxf(m[h], __shfl_xor(m[h], off));
                }
                #pragma unroll
                for (int h = 0; h < 4; ++h) { p[h] = (j < end) ? __expf(lv[h] - m[h]) : 0.f; s[h] = p[h]; }
                #pragma unroll
                for (int off = 1; off < 64; off <<= 1) {
                    #pragma unroll
                    for (int h = 0; h < 4; ++h) s[h] += __shfl_xor(s[h], off);
                }
                lalpha[w][l] = make_float4(p[0] / s[0], p[1] / s[1], p[2] / s[2], p[3] / s[3]);
                lcol[w][l] = (unsigned)cj << 8;
                __builtin_amdgcn_wave_barrier();
                for (int i = 0; i < deg; i += 4) {
                    float4 pa0 = lalpha[w][i],     pa1 = lalpha[w][i + 1];
                    float4 pa2 = lalpha[w][i + 2], pa3 = lalpha[w][i + 3];
                    unsigned o0 = lcol[w][i] | l4,     o1 = lcol[w][i + 1] | l4;
                    unsigned o2 = lcol[w][i + 2] | l4, o3 = lcol[w][i + 3] | l4;
                    unsigned x0 = *reinterpret_cast<const unsigned*>(Xb + o0);
                    unsigned x1 = *reinterpret_cast<const unsigned*>(Xb + o1);
                    unsigned x2 = *reinterpret_cast<const unsigned*>(Xb + o2);
                    unsigned x3 = *reinterpret_cast<const unsigned*>(Xb + o3);
                    EDGEF(x0, pa0) EDGEF(x1, pa1) EDGEF(x2, pa2) EDGEF(x3, pa3)
                }
                __builtin_amdgcn_wave_barrier();   // reads done before next node reuses lalpha
            } else {
                float m[4] = {-1e30f, -1e30f, -1e30f, -1e30f}, s[4] = {0.f, 0.f, 0.f, 0.f};
                for (int base = start; base < end; base += 64) {
                    const int j = base + l;
                    float lv[4] = {-1e30f, -1e30f, -1e30f, -1e30f};
                    if (j < end) {
                        float4 a = as4[col[j]];
                        lv[0] = a.x + ad4.x; lv[1] = a.y + ad4.y; lv[2] = a.z + ad4.z; lv[3] = a.w + ad4.w;
                        #pragma unroll
                        for (int h = 0; h < 4; ++h) lv[h] = lv[h] > 0.f ? lv[h] : 0.2f * lv[h];
                    }
                    float cm[4], cp[4];
                    #pragma unroll
                    for (int h = 0; h < 4; ++h) cm[h] = lv[h];
                    #pragma unroll
                    for (int off = 1; off < 64; off <<= 1) {
                        #pragma unroll
                        for (int h = 0; h < 4; ++h) cm[h] = fmaxf(cm[h], __shfl_xor(cm[h], off));
                    }
                    #pragma unroll
                    for (int h = 0; h < 4; ++h) {
                        float nm = fmaxf(m[h], cm[h]);
                        cp[h] = (j < end) ? __expf(lv[h] - nm) : 0.f;
                        s[h] *= __expf(m[h] - nm);
                        m[h] = nm;
                    }
                    #pragma unroll
                    for (int off = 1; off < 64; off <<= 1) {
                        #pragma unroll
                        for (int h = 0; h < 4; ++h) cp[h] += __shfl_xor(cp[h], off);
                    }
                    #pragma unroll
                    for (int h = 0; h < 4; ++h) s[h] += cp[h];
                }
                for (int base = start; base < end; base += 64) {
                    const int j = base + l;
                    if (j < end) {
                        int cj = col[j];
                        float4 a = as4[cj];
                        float v0 = a.x + ad4.x, v1 = a.y + ad4.y, v2 = a.z + ad4.z, v3 = a.w + ad4.w;
                        v0 = v0 > 0.f ? v0 : 0.2f * v0; v1 = v1 > 0.f ? v1 : 0.2f * v1;
                        v2 = v2 > 0.f ? v2 : 0.2f * v2; v3 = v3 > 0.f ? v3 : 0.2f * v3;
                        __half2 a01 = __floats2half2_rn(__expf(v0 - m[0]) / s[0], __expf(v1 - m[1]) / s[1]);
                        __half2 a23 = __floats2half2_rn(__expf(v2 - m[2]) / s[2], __expf(v3 - m[3]) / s[3]);
                        uint4 rr;
                        rr.x = *reinterpret_cast<unsigned*>(&a01);
                        rr.y = *reinterpret_cast<unsigned*>(&a23);
                        rr.z = (unsigned)cj;
                        rr.w = 0;
                        rec[j] = rr;
                    }
                }
                __threadfence_block();
                const unsigned* __restrict__ X4 = reinterpret_cast<const unsigned*>(X);
                int j = start;
                for (; j + 4 <= end; j += 4) {
                    uint4 r0 = rec[j], r1 = rec[j + 1], r2 = rec[j + 2], r3 = rec[j + 3];
                    unsigned x0 = X4[(size_t)r0.z * 64 + l];
                    unsigned x1 = X4[(size_t)r1.z * 64 + l];
                    unsigned x2 = X4[(size_t)r2.z * 64 + l];
                    unsigned x3 = X4[(size_t)r3.z * 64 + l];
                    EDGE(x0, r0) EDGE(x1, r1) EDGE(x2, r2) EDGE(x3, r3)
                }
                for (; j < end; ++j) {
                    uint4 r0 = rec[j];
                    unsigned x0 = X4[(size_t)r0.z * 64 + l];
                    EDGE(x0, r0)
                }
            }
        }
        // write agg row (bf16-rounded; zeros for pad nodes) to swizzled LDS
        #pragma unroll
        for (int h = 0; h < 4; ++h) {
            union { bf16 b; unsigned short u; } plo, phi;
            plo.b = __float2bfloat16(acc2[h].x);
            phi.b = __float2bfloat16(acc2[h].y);
            unsigned u = (unsigned)plo.u | ((unsigned)phi.u << 16);
            *reinterpret_cast<unsigned*>(rowp + ((h * 256 + l4) ^ swz)) = u;
        }
    }
    __syncthreads();
    // ================= MFMA phase: 16x128 tile, wave w -> cols [w*32, w*32+32) =================
    const int lr = l & 15;
    const int lkb = (l >> 4) * 16;
    const char* Asr = As + lr * 1024;
    const unsigned aswz = (unsigned)((lr & 7) << 4);
    const char* Bb = (const char*)Bt + (size_t)(w * 32) * 1024;
    f32x4 acc[2] = {};
    #pragma unroll 4
    for (int ks = 0; ks < 16; ++ks) {
        int kg = ks * 64;
        bf16x8 a  = *(const bf16x8*)(Asr + ((kg + lkb) ^ aswz));
        bf16x8 b0 = *(const bf16x8*)(Bb + (size_t)lr * 1024 + kg + lkb);
        bf16x8 b1 = *(const bf16x8*)(Bb + (size_t)(16 + lr) * 1024 + kg + lkb);
        acc[0] = __builtin_amdgcn_mfma_f32_16x16x32_bf16(a, b0, acc[0], 0, 0, 0);
        acc[1] = __builtin_amdgcn_mfma_f32_16x16x32_bf16(a, b1, acc[1], 0, 0, 0);
    }
    const int orow = (l >> 4) * 4;
    float cs[2] = {0.f, 0.f}, cq[2] = {0.f, 0.f};
    #pragma unroll
    for (int nf = 0; nf < 2; ++nf) {
        int c = w * 32 + nf * 16 + lr;
        float bc = bias[c];
        #pragma unroll
        for (int r4 = 0; r4 < 4; ++r4) {
            int gr = m0 + orow + r4;
            if (gr < M) {
                float v = acc[nf][r4] + bc;
                outb[(size_t)gr * DF + c] = __float2bfloat16(v);
                cs[nf] += v; cq[nf] += v * v;
            }
        }
    }
    #pragma unroll
    for (int nf = 0; nf < 2; ++nf) {
        cs[nf] += __shfl_xor(cs[nf], 16);  cq[nf] += __shfl_xor(cq[nf], 16);
        cs[nf] += __shfl_xor(cs[nf], 32);  cq[nf] += __shfl_xor(cq[nf], 32);
    }
    if (l < 16) {
        float* sp = scratch + (size_t)blockIdx.x * 256;
        #pragma unroll
        for (int nf = 0; nf < 2; ++nf) {
            int c = w * 32 + nf * 16 + l;
            sp[c] = cs[nf];
            sp[128 + c] = cq[nf];
        }
    }
}

// ---------- reduce per-block BN partials: stats[t] = sum over blocks ----------
__global__ __launch_bounds__(256) void stats_reduce(const float* __restrict__ scratch,
                                                    float* __restrict__ stats) {
    const int t = blockIdx.x;              // 0..255: col (t<128: sum, else sumsq)
    float s = 0.f;
    for (int i = threadIdx.x; i < GB; i += 256)
        s += scratch[(size_t)i * 256 + t];
    __shared__ float sd[256];
    sd[threadIdx.x] = s;
    __syncthreads();
    for (int o = 128; o > 0; o >>= 1) {
        if (threadIdx.x < o) sd[threadIdx.x] += sd[threadIdx.x + o];
        __syncthreads();
    }
    if (threadIdx.x == 0) stats[t] = sd[0];
}

// ---------- BatchNorm apply (bf16 input, 8 elems/thread) ----------
__device__ __forceinline__ void bn_core(const uint4 v, int c0, const float* stats,
                                        const float* gamma, const float* beta, float* o) {
    float xv[8];
    xv[0] = __uint_as_float(v.x << 16); xv[1] = __uint_as_float(v.x & 0xffff0000u);
    xv[2] = __uint_as_float(v.y << 16); xv[3] = __uint_as_float(v.y & 0xffff0000u);
    xv[4] = __uint_as_float(v.z << 16); xv[5] = __uint_as_float(v.z & 0xffff0000u);
    xv[6] = __uint_as_float(v.w << 16); xv[7] = __uint_as_float(v.w & 0xffff0000u);
    #pragma unroll
    for (int k = 0; k < 8; ++k) {
        int c = c0 + k;
        float mu = stats[c] * (1.f / NN);
        float var = stats[128 + c] * (1.f / NN) - mu * mu;
        o[k] = fmaxf((xv[k] - mu) * rsqrtf(var + BN_EPS) * gamma[c] + beta[c], 0.f);
    }
}

__global__ __launch_bounds__(256) void bn_apply_bf16(const bf16* __restrict__ x, const float* __restrict__ stats,
                                                     const float* __restrict__ gamma, const float* __restrict__ beta,
                                                     bf16* __restrict__ out) {
    int i = blockIdx.x * 256 + threadIdx.x;
    if (i >= NN * DF / 8) return;
    uint4 v = reinterpret_cast<const uint4*>(x)[i];
    float o[8];
    bn_core(v, (i * 8) & 127, stats, gamma, beta, o);
    uint4 w;
    unsigned short* wb = reinterpret_cast<unsigned short*>(&w);
    #pragma unroll
    for (int k = 0; k < 8; ++k) {
        union { bf16 b; unsigned short u; } t;
        t.b = __float2bfloat16(o[k]);
        wb[k] = t.u;
    }
    reinterpret_cast<uint4*>(out)[i] = w;
}

__global__ __launch_bounds__(256) void bn_apply_f32(const bf16* __restrict__ x, const float* __restrict__ stats,
                                                    const float* __restrict__ gamma, const float* __restrict__ beta,
                                                    float* __restrict__ out) {
    int i = blockIdx.x * 256 + threadIdx.x;
    if (i >= NN * DF / 8) return;
    uint4 v = reinterpret_cast<const uint4*>(x)[i];
    float o[8];
    bn_core(v, (i * 8) & 127, stats, gamma, beta, o);
    float4* op = reinterpret_cast<float4*>(out) + (size_t)i * 2;
    op[0] = make_float4(o[0], o[1], o[2], o[3]);
    op[1] = make_float4(o[4], o[5], o[6], o[7]);
}

extern "C" void kernel_launch(void* const* d_in, const int* in_sizes, int n_in,
                              void* d_out, int out_size, void* d_ws, size_t ws_size,
                              hipStream_t stream) {
    (void)in_sizes; (void)n_in; (void)out_size; (void)ws_size;
    const float* x   = (const float*)d_in[0];
    const int*   ei  = (const int*)d_in[1];
    const float* W1  = (const float*)d_in[2];
    const float* as1 = (const float*)d_in[3];
    const float* ad1 = (const float*)d_in[4];
    const float* b1  = (const float*)d_in[5];
    const float* g1  = (const float*)d_in[6];
    const float* be1 = (const float*)d_in[7];
    const float* W2  = (const float*)d_in[8];
    const float* as2 = (const float*)d_in[9];
    const float* ad2 = (const float*)d_in[10];
    const float* b2  = (const float*)d_in[11];
    const float* g2  = (const float*)d_in[12];
    const float* be2 = (const float*)d_in[13];
    float* out = (float*)d_out;

    char* ws = (char*)d_ws;
    size_t off = 0;
    auto alloc = [&](size_t bytes) -> void* {
        void* p = ws + off;
        off += (bytes + 255) & ~(size_t)255;
        return p;
    };
    bf16*   xb      = (bf16*)alloc((size_t)NP * DF * 2);      // 12.8 MB (padded)
    bf16*   Bt2a    = (bf16*)alloc((size_t)DF * HD * 2);      // 128 KB
    bf16*   Bt2b    = (bf16*)alloc((size_t)DF * HD * 2);
    float*  wsd     = (float*)alloc(2 * 1024 * 4);            // 8 KB
    float*  a_src   = (float*)alloc((size_t)NN * NH * 4);
    float*  a_dst   = (float*)alloc((size_t)NN * NH * 4);
    int*    row_ptr = (int*)alloc((size_t)(NN + 1) * 4);
    int*    bsum    = (int*)alloc(256 * 4);
    int*    colidx  = (int*)alloc((size_t)ET * 4);
    uint4*  rec     = (uint4*)alloc((size_t)ET * 16);         // 13.6 MB (deg>64 path only)
    bf16*   agg     = (bf16*)alloc((size_t)NN * DF * 2);      // 12.8 MB
    float*  stats   = (float*)alloc(256 * 4);
    float*  scratch = (float*)alloc((size_t)GB * 256 * 4);    // 3.2 MB
    // counts (padded 64B/dst, 3.2MB) + rank (3.4MB) aliased into agg (12.8MB;
    // agg first written by agg_gemm, long after CSR build completes)
    int*    counts  = (int*)agg;
    int*    rank    = (int*)((char*)agg + ((size_t)NP << 6));
    // high-water ~41 MB (<= R1-proven 107.4 MB)

    const int NB = (NN + 255) / 256;        // 196
    const int EB2 = (ET / 2 + 255) / 256;   // 1661
    const int BNB = (NN * DF / 8 + 255) / 256;  // 3125

    // ---- prep + CSR build (single atomic pass) ----
    cvt_x_bf16<<<(NN * DF / 4 + 255) / 256, 256, 0, stream>>>(x, xb);
    make_wsd<<<8, 256, 0, stream>>>(W1, as1, ad1, W2, as2, ad2, wsd);
    cvt_bt2<<<(2 * DF * HD + 255) / 256, 256, 0, stream>>>(W1, W2, Bt2a, Bt2b);
    hipMemsetAsync(counts, 0, (size_t)NP << 6, stream);
    count_rank<<<EB2, 256, 0, stream>>>(ei, counts, rank);
    scan1<<<NB, 256, 0, stream>>>(counts, bsum);
    scan2<<<1, 256, 0, stream>>>(bsum, NB);
    scan3<<<NB, 256, 0, stream>>>(counts, bsum, row_ptr);
    fill_scatter<<<EB2, 256, 0, stream>>>(ei, rank, row_ptr, colidx);

    // ---- layer 1 ----
    xscore<<<NN / 4, 256, 0, stream>>>(xb, wsd, a_src, a_dst);
    agg_gemm<<<GB, 256, 0, stream>>>(xb, a_src, a_dst, row_ptr, colidx, rec, Bt2a, b1, agg, scratch, NN);
    stats_reduce<<<256, 256, 0, stream>>>(scratch, stats);
    bn_apply_bf16<<<BNB, 256, 0, stream>>>(agg, stats, g1, be1, xb);

    // ---- layer 2 ----
    xscore<<<NN / 4, 256, 0, stream>>>(xb, wsd + 1024, a_src, a_dst);
    agg_gemm<<<GB, 256, 0, stream>>>(xb, a_src, a_dst, row_ptr, colidx, rec, Bt2b, b2, agg, scratch, NN);
    stats_reduce<<<256, 256, 0, stream>>>(scratch, stats);
    bn_apply_f32<<<BNB, 256, 0, stream>>>(agg, stats, g2, be2, out);
}

// Round 21
// 324.424 us; speedup vs baseline: 1.0803x; 1.0803x over previous
//
#include <hip/hip_runtime.h>
#include <hip/hip_bf16.h>
#include <hip/hip_fp16.h>
#include <math.h>

#define NN 50000
#define NP 50048            // NN padded to 64-row tiles
#define NE 800000
#define ET (NE + NN)
#define DF 128
#define NH 4
#define HD 512
#define BN_EPS 1e-5f

typedef __hip_bfloat16 bf16;
typedef __attribute__((ext_vector_type(8))) short bf16x8;
typedef __attribute__((ext_vector_type(4))) float f32x4;
typedef __attribute__((ext_vector_type(2))) float f32x2;

// ---------- input conversions ----------
__global__ __launch_bounds__(256) void cvt_x_bf16(const float* __restrict__ in, bf16* __restrict__ out) {
    int i = blockIdx.x * 256 + threadIdx.x;            // 4 elements per thread
    if (i >= NN * DF / 4) return;
    float4 v = reinterpret_cast<const float4*>(in)[i];
    union { bf16 b[4]; short4 s; } u;
    u.b[0] = __float2bfloat16(v.x); u.b[1] = __float2bfloat16(v.y);
    u.b[2] = __float2bfloat16(v.z); u.b[3] = __float2bfloat16(v.w);
    reinterpret_cast<short4*>(out)[i] = u.s;
}

// wsd[layer][o][d] = sum_c W[d, h*128+c] * att[h][c],  o=h (src, 0..3) or 4+h (dst)
__global__ __launch_bounds__(256) void make_wsd(const float* __restrict__ W1, const float* __restrict__ as1,
                                                const float* __restrict__ ad1,
                                                const float* __restrict__ W2, const float* __restrict__ as2,
                                                const float* __restrict__ ad2,
                                                float* __restrict__ wsd) {
    int t = blockIdx.x * 256 + threadIdx.x;   // 0..2047
    if (t >= 2048) return;
    int layer = t >> 10;
    int o = (t >> 7) & 7;
    int d = t & 127;
    int h = o & 3;
    const float* W  = layer ? W2 : W1;
    const float* av = layer ? (o < 4 ? as2 : ad2) : (o < 4 ? as1 : ad1);
    const float* wrow = W + d * HD + h * DF;
    const float* arow = av + h * DF;
    float sum = 0.f;
    for (int c = 0; c < DF; ++c) sum += wrow[c] * arow[c];
    wsd[layer * 1024 + o * DF + d] = sum;
}

// Bt2[layer][c][h*128+d] = 0.25 * W[d][h*128+c]   (stacked, transposed, head-mean folded)
__global__ __launch_bounds__(256) void cvt_bt2(const float* __restrict__ W1, const float* __restrict__ W2,
                                               bf16* __restrict__ B1, bf16* __restrict__ B2) {
    int i = blockIdx.x * 256 + threadIdx.x;   // 0..131071
    if (i >= 2 * DF * HD) return;
    int layer = i >> 16;
    int ii = i & 65535;
    int c = ii >> 9, k = ii & 511;
    int h = k >> 7, d = k & 127;
    const float* W = layer ? W2 : W1;
    bf16* B = layer ? B2 : B1;
    B[ii] = __float2bfloat16(0.25f * W[d * HD + h * DF + c]);
}

// ---------- per-node scores from x (+ stats zeroing in block 0) ----------
__global__ __launch_bounds__(256) void xscore(const bf16* __restrict__ X,
                                              const float* __restrict__ wsd,   // [8][128]
                                              float* __restrict__ a_src,
                                              float* __restrict__ a_dst,
                                              float* __restrict__ stats) {
    if (blockIdx.x == 0 && threadIdx.x < 64)
        reinterpret_cast<float4*>(stats)[threadIdx.x] = make_float4(0.f, 0.f, 0.f, 0.f);
    __shared__ float w[8][DF];
    reinterpret_cast<float4*>(&w[0][0])[threadIdx.x] = reinterpret_cast<const float4*>(wsd)[threadIdx.x];
    __syncthreads();
    const int n = blockIdx.x * 4 + (threadIdx.x >> 6);
    const int l = threadIdx.x & 63;          // lane owns features 2l, 2l+1
    unsigned xv = reinterpret_cast<const unsigned*>(X)[n * 64 + l];
    float x0 = __uint_as_float(xv << 16);
    float x1 = __uint_as_float(xv & 0xffff0000u);
    float v[8];
    #pragma unroll
    for (int o = 0; o < 8; ++o)
        v[o] = x0 * w[o][2 * l] + x1 * w[o][2 * l + 1];
    #pragma unroll
    for (int off = 1; off < 64; off <<= 1) {
        #pragma unroll
        for (int o = 0; o < 8; ++o) v[o] += __shfl_xor(v[o], off);
    }
    if (l == 0) {
        reinterpret_cast<float4*>(a_src)[n] = make_float4(v[0], v[1], v[2], v[3]);
        reinterpret_cast<float4*>(a_dst)[n] = make_float4(v[4], v[5], v[6], v[7]);
    }
}

// ---------- CSR build: single atomic pass (rank trick) ----------
__global__ __launch_bounds__(256) void count_rank(const int* __restrict__ ei, int* __restrict__ counts,
                                                  int* __restrict__ rank) {
    int e = (blockIdx.x * 256 + threadIdx.x) * 2;
    if (e >= ET) return;
    int d0, d1;
    if (e + 1 < NE) {
        int2 dd = *reinterpret_cast<const int2*>(ei + NE + e);
        d0 = dd.x; d1 = dd.y;
    } else {
        d0 = (e < NE) ? ei[NE + e] : (e - NE);
        d1 = (e + 1 < NE) ? ei[NE + e + 1] : (e + 1 - NE);
    }
    rank[e]     = atomicAdd(&counts[d0 << 4], 1);
    rank[e + 1] = atomicAdd(&counts[d1 << 4], 1);
}

__global__ __launch_bounds__(256) void scan1(const int* __restrict__ counts, int* __restrict__ bsum) {
    __shared__ int sd[256];
    int i = blockIdx.x * 256 + threadIdx.x;
    sd[threadIdx.x] = (i < NN) ? counts[i << 4] : 0;
    __syncthreads();
    for (int s = 128; s > 0; s >>= 1) {
        if (threadIdx.x < s) sd[threadIdx.x] += sd[threadIdx.x + s];
        __syncthreads();
    }
    if (threadIdx.x == 0) bsum[blockIdx.x] = sd[0];
}

// parallel exclusive scan over <=256 block sums (Hillis-Steele)
__global__ __launch_bounds__(256) void scan2(int* __restrict__ bsum, int nb) {
    __shared__ int sd[256];
    int i = threadIdx.x;
    int v = (i < nb) ? bsum[i] : 0;
    sd[i] = v;
    __syncthreads();
    for (int s = 1; s < 256; s <<= 1) {
        int t = sd[i];
        int u = (i >= s) ? sd[i - s] : 0;
        __syncthreads();
        sd[i] = t + u;
        __syncthreads();
    }
    if (i < nb) bsum[i] = sd[i] - v;
}

__global__ __launch_bounds__(256) void scan3(const int* __restrict__ counts, const int* __restrict__ bsum,
                                             int* __restrict__ row_ptr) {
    __shared__ int sd[256];
    int i = blockIdx.x * 256 + threadIdx.x;
    int v = (i < NN) ? counts[i << 4] : 0;
    sd[threadIdx.x] = v;
    __syncthreads();
    for (int s = 1; s < 256; s <<= 1) {
        int t = sd[threadIdx.x];
        int u = (threadIdx.x >= s) ? sd[threadIdx.x - s] : 0;
        __syncthreads();
        sd[threadIdx.x] = t + u;
        __syncthreads();
    }
    int excl = sd[threadIdx.x] - v + bsum[blockIdx.x];
    if (i < NN) row_ptr[i] = excl;
    if (i == 0) row_ptr[NN] = ET;
}

// non-atomic scatter: col[row_ptr[d] + rank[e]] = src(e)
__global__ __launch_bounds__(256) void fill_scatter(const int* __restrict__ ei, const int* __restrict__ rank,
                                                    const int* __restrict__ row_ptr, int* __restrict__ col) {
    int e = (blockIdx.x * 256 + threadIdx.x) * 2;
    if (e >= ET) return;
    int s0, d0, s1, d1;
    if (e + 1 < NE) {
        int2 ss = *reinterpret_cast<const int2*>(ei + e);
        int2 dd = *reinterpret_cast<const int2*>(ei + NE + e);
        s0 = ss.x; s1 = ss.y; d0 = dd.x; d1 = dd.y;
    } else {
        if (e < NE) { s0 = ei[e]; d0 = ei[NE + e]; } else { s0 = d0 = e - NE; }
        if (e + 1 < NE) { s1 = ei[e + 1]; d1 = ei[NE + e + 1]; } else { s1 = d1 = e + 1 - NE; }
    }
    int2 rk = *reinterpret_cast<const int2*>(rank + e);
    col[row_ptr[d0] + rk.x] = s0;
    col[row_ptr[d1] + rk.y] = s1;
}

// ---------- fused alpha + gather: one WAVE per node ----------
// deg<=64: f32 alphas in LDS, col as pre-scaled byte offset (1 OR per gather),
// packed f32x2 accumulation (v_pk_fma_f32: 4 insts/edge).
// deg>64: R17's proven global-rec flow (also packed acc).
#define EDGEF(xu, pa) {                                                              \
    f32x2 xv;                                                                        \
    xv.x = __uint_as_float((xu) << 16);                                              \
    xv.y = __uint_as_float((xu) & 0xffff0000u);                                      \
    acc2[0] += (pa).x * xv;                                                          \
    acc2[1] += (pa).y * xv;                                                          \
    acc2[2] += (pa).z * xv;                                                          \
    acc2[3] += (pa).w * xv; }

#define EDGE(xu, r) {                                                                \
    f32x2 xv;                                                                        \
    xv.x = __uint_as_float((xu) << 16);                                              \
    xv.y = __uint_as_float((xu) & 0xffff0000u);                                      \
    float2 f01 = __half22float2(*reinterpret_cast<const __half2*>(&(r).x));          \
    float2 f23 = __half22float2(*reinterpret_cast<const __half2*>(&(r).y));          \
    acc2[0] += f01.x * xv;                                                           \
    acc2[1] += f01.y * xv;                                                           \
    acc2[2] += f23.x * xv;                                                           \
    acc2[3] += f23.y * xv; }

__global__ __launch_bounds__(256) void agg_fused(const bf16* __restrict__ X,
                                                 const float* __restrict__ a_src,
                                                 const float* __restrict__ a_dst,
                                                 const int* __restrict__ row_ptr,
                                                 const int* __restrict__ col,
                                                 uint4* __restrict__ rec,
                                                 bf16* __restrict__ aggX) {
    __shared__ __align__(16) float4 lalpha[4][64];
    __shared__ unsigned lcol[4][64];
    const int w = threadIdx.x >> 6;
    const int n = blockIdx.x * 4 + w;
    const int l = threadIdx.x & 63;
    const unsigned l4 = (unsigned)l << 2;         // byte offset within 256B row
    const int start = row_ptr[n], end = row_ptr[n + 1];
    const int deg = end - start;
    const float4 ad4 = reinterpret_cast<const float4*>(a_dst)[n];
    const float4* __restrict__ as4 = reinterpret_cast<const float4*>(a_src);
    const char* __restrict__ Xb = reinterpret_cast<const char*>(X);
    f32x2 acc2[4] = {};
    if (deg <= 64) {
        // ---- phase A: lane l handles edge start+l ----
        const int j = start + l;
        int cj = 0;
        float lv[4] = {-1e30f, -1e30f, -1e30f, -1e30f};
        if (j < end) {
            cj = col[j];
            float4 a = as4[cj];
            lv[0] = a.x + ad4.x; lv[1] = a.y + ad4.y; lv[2] = a.z + ad4.z; lv[3] = a.w + ad4.w;
            #pragma unroll
            for (int h = 0; h < 4; ++h) lv[h] = lv[h] > 0.f ? lv[h] : 0.2f * lv[h];
        }
        float m[4], p[4], s[4];
        #pragma unroll
        for (int h = 0; h < 4; ++h) m[h] = lv[h];
        #pragma unroll
        for (int off = 1; off < 64; off <<= 1) {
            #pragma unroll
            for (int h = 0; h < 4; ++h) m[h] = fmaxf(m[h], __shfl_xor(m[h], off));
        }
        #pragma unroll
        for (int h = 0; h < 4; ++h) { p[h] = (j < end) ? __expf(lv[h] - m[h]) : 0.f; s[h] = p[h]; }
        #pragma unroll
        for (int off = 1; off < 64; off <<= 1) {
            #pragma unroll
            for (int h = 0; h < 4; ++h) s[h] += __shfl_xor(s[h], off);
        }
        lalpha[w][l] = make_float4(p[0] / s[0], p[1] / s[1], p[2] / s[2], p[3] / s[3]);
        lcol[w][l] = (unsigned)cj << 8;            // row byte offset (pads: 0 with alpha 0)
        __builtin_amdgcn_wave_barrier();
        // ---- phase B: unroll-4, no masking (pad records are zero) ----
        for (int i = 0; i < deg; i += 4) {
            float4 pa0 = lalpha[w][i],     pa1 = lalpha[w][i + 1];
            float4 pa2 = lalpha[w][i + 2], pa3 = lalpha[w][i + 3];
            unsigned o0 = lcol[w][i] | l4,     o1 = lcol[w][i + 1] | l4;
            unsigned o2 = lcol[w][i + 2] | l4, o3 = lcol[w][i + 3] | l4;
            unsigned x0 = *reinterpret_cast<const unsigned*>(Xb + o0);
            unsigned x1 = *reinterpret_cast<const unsigned*>(Xb + o1);
            unsigned x2 = *reinterpret_cast<const unsigned*>(Xb + o2);
            unsigned x3 = *reinterpret_cast<const unsigned*>(Xb + o3);
            EDGEF(x0, pa0) EDGEF(x1, pa1) EDGEF(x2, pa2) EDGEF(x3, pa3)
        }
    } else {
        // ---- phase A (chunked, rare): writes global rec ----
        float m[4] = {-1e30f, -1e30f, -1e30f, -1e30f}, s[4] = {0.f, 0.f, 0.f, 0.f};
        for (int base = start; base < end; base += 64) {
            const int j = base + l;
            float lv[4] = {-1e30f, -1e30f, -1e30f, -1e30f};
            if (j < end) {
                float4 a = as4[col[j]];
                lv[0] = a.x + ad4.x; lv[1] = a.y + ad4.y; lv[2] = a.z + ad4.z; lv[3] = a.w + ad4.w;
                #pragma unroll
                for (int h = 0; h < 4; ++h) lv[h] = lv[h] > 0.f ? lv[h] : 0.2f * lv[h];
            }
            float cm[4], cp[4];
            #pragma unroll
            for (int h = 0; h < 4; ++h) cm[h] = lv[h];
            #pragma unroll
            for (int off = 1; off < 64; off <<= 1) {
                #pragma unroll
                for (int h = 0; h < 4; ++h) cm[h] = fmaxf(cm[h], __shfl_xor(cm[h], off));
            }
            #pragma unroll
            for (int h = 0; h < 4; ++h) {
                float nm = fmaxf(m[h], cm[h]);
                cp[h] = (j < end) ? __expf(lv[h] - nm) : 0.f;
                s[h] *= __expf(m[h] - nm);
                m[h] = nm;
            }
            #pragma unroll
            for (int off = 1; off < 64; off <<= 1) {
                #pragma unroll
                for (int h = 0; h < 4; ++h) cp[h] += __shfl_xor(cp[h], off);
            }
            #pragma unroll
            for (int h = 0; h < 4; ++h) s[h] += cp[h];
        }
        for (int base = start; base < end; base += 64) {
            const int j = base + l;
            if (j < end) {
                int cj = col[j];
                float4 a = as4[cj];
                float v0 = a.x + ad4.x, v1 = a.y + ad4.y, v2 = a.z + ad4.z, v3 = a.w + ad4.w;
                v0 = v0 > 0.f ? v0 : 0.2f * v0; v1 = v1 > 0.f ? v1 : 0.2f * v1;
                v2 = v2 > 0.f ? v2 : 0.2f * v2; v3 = v3 > 0.f ? v3 : 0.2f * v3;
                __half2 a01 = __floats2half2_rn(__expf(v0 - m[0]) / s[0], __expf(v1 - m[1]) / s[1]);
                __half2 a23 = __floats2half2_rn(__expf(v2 - m[2]) / s[2], __expf(v3 - m[3]) / s[3]);
                uint4 r;
                r.x = *reinterpret_cast<unsigned*>(&a01);
                r.y = *reinterpret_cast<unsigned*>(&a23);
                r.z = (unsigned)cj;
                r.w = 0;
                rec[j] = r;
            }
        }
        __threadfence_block();                      // drain stores before re-reading
        const unsigned* __restrict__ X4 = reinterpret_cast<const unsigned*>(X);
        int j = start;
        for (; j + 4 <= end; j += 4) {
            uint4 r0 = rec[j], r1 = rec[j + 1], r2 = rec[j + 2], r3 = rec[j + 3];
            unsigned x0 = X4[(size_t)r0.z * 64 + l];
            unsigned x1 = X4[(size_t)r1.z * 64 + l];
            unsigned x2 = X4[(size_t)r2.z * 64 + l];
            unsigned x3 = X4[(size_t)r3.z * 64 + l];
            EDGE(x0, r0) EDGE(x1, r1) EDGE(x2, r2) EDGE(x3, r3)
        }
        for (; j < end; ++j) {
            uint4 r0 = rec[j];
            unsigned x0 = X4[(size_t)r0.z * 64 + l];
            EDGE(x0, r0)
        }
    }
    unsigned* outp = reinterpret_cast<unsigned*>(aggX) + (size_t)n * 256;
    #pragma unroll
    for (int h = 0; h < 4; ++h) {
        union { bf16 b; unsigned short u; } plo, phi;
        plo.b = __float2bfloat16(acc2[h].x);
        phi.b = __float2bfloat16(acc2[h].y);
        outp[h * 64 + l] = (unsigned)plo.u | ((unsigned)phi.u << 16);
    }
}

// ---------- MFMA GEMM: agg[M,128](bf16) = A[M,512](bf16) @ Bt[128,512]^T + bias ----------
// B LDS-resident in two 64KB K-phases; A streamed global->VGPR (no barriers in main loop).
__global__ __launch_bounds__(256) void gemm_out(const bf16* __restrict__ A,
                                                const bf16* __restrict__ Bt,
                                                const float* __restrict__ bias,
                                                bf16* __restrict__ outb,
                                                float* __restrict__ stats, int M) {
    __shared__ __align__(16) char Bs[65536];      // [128 cols][512B K-phase], XOR-swizzled
    __shared__ float ssum[128], ssq[128];
    const int tid = threadIdx.x;
    if (tid < 128) { ssum[tid] = 0.f; ssq[tid] = 0.f; }
    const int m0 = blockIdx.x * 64;
    const char* Ab = (const char*)A + (size_t)m0 * 1024;     // row stride 512*2 B
    const char* Bb = (const char*)Bt;
    auto stageB = [&](int ph) {
        #pragma unroll
        for (int i = 0; i < 16; ++i) {
            int d = (tid + i * 256) * 16;        // 0..65535
            int c = d >> 9;                      // col 0..127
            int kb = d & 511;
            int src = c * 1024 + ph * 512 + (kb ^ ((c & 7) << 4));
            __builtin_amdgcn_global_load_lds(
                (const __attribute__((address_space(1))) void*)(Bb + src),
                (__attribute__((address_space(3))) void*)(Bs + d), 16, 0, 0);
        }
    };
    const int lane = tid & 63;
    const int wave = tid >> 6;
    const int wm = (wave & 1) * 32;               // m-offset
    const int wnb = (wave >> 1) * 64;             // col base (0 or 64)
    const int lr = lane & 15;
    const int lkb = (lane >> 4) * 16;
    f32x4 acc[2][4] = {};
    const char* arow0 = Ab + (size_t)(wm + lr) * 1024 + lkb;
    const char* arow1 = Ab + (size_t)(wm + 16 + lr) * 1024 + lkb;
    stageB(0);
    #pragma unroll
    for (int ph = 0; ph < 2; ++ph) {
        __syncthreads();                          // stage(ph) complete
        #pragma unroll 4
        for (int kk = 0; kk < 8; ++kk) {
            int kg = ph * 512 + kk * 64;
            bf16x8 a0 = *(const bf16x8*)(arow0 + kg);
            bf16x8 a1 = *(const bf16x8*)(arow1 + kg);
            int kb = kk * 64 + lkb;
            #pragma unroll
            for (int nf = 0; nf < 4; ++nf) {
                int c = wnb + nf * 16 + lr;
                bf16x8 b = *(const bf16x8*)(Bs + c * 512 + (kb ^ ((c & 7) << 4)));
                acc[0][nf] = __builtin_amdgcn_mfma_f32_16x16x32_bf16(a0, b, acc[0][nf], 0, 0, 0);
                acc[1][nf] = __builtin_amdgcn_mfma_f32_16x16x32_bf16(a1, b, acc[1][nf], 0, 0, 0);
            }
        }
        if (ph == 0) {
            __syncthreads();                      // all reads of phase-0 B done
            stageB(1);
        }
    }
    const int orow = (lane >> 4) * 4;
    float bcol[4];
    #pragma unroll
    for (int nf = 0; nf < 4; ++nf) bcol[nf] = bias[wnb + nf * 16 + lr];
    #pragma unroll
    for (int nf = 0; nf < 4; ++nf) {
        float cs = 0.f, cq = 0.f;
        int c = wnb + nf * 16 + lr;
        #pragma unroll
        for (int mi = 0; mi < 2; ++mi) {
            #pragma unroll
            for (int r = 0; r < 4; ++r) {
                int gr = m0 + wm + mi * 16 + orow + r;
                if (gr < M) {
                    float v = acc[mi][nf][r] + bcol[nf];
                    outb[(size_t)gr * DF + c] = __float2bfloat16(v);
                    cs += v; cq += v * v;
                }
            }
        }
        atomicAdd(&ssum[c], cs);
        atomicAdd(&ssq[c], cq);
    }
    __syncthreads();
    if (tid < 128) {
        atomicAdd(&stats[tid], ssum[tid]);
        atomicAdd(&stats[128 + tid], ssq[tid]);
    }
}

// ---------- BatchNorm apply (bf16 input, 8 elems/thread) ----------
__device__ __forceinline__ void bn_core(const uint4 v, int c0, const float* stats,
                                        const float* gamma, const float* beta, float* o) {
    float xv[8];
    xv[0] = __uint_as_float(v.x << 16); xv[1] = __uint_as_float(v.x & 0xffff0000u);
    xv[2] = __uint_as_float(v.y << 16); xv[3] = __uint_as_float(v.y & 0xffff0000u);
    xv[4] = __uint_as_float(v.z << 16); xv[5] = __uint_as_float(v.z & 0xffff0000u);
    xv[6] = __uint_as_float(v.w << 16); xv[7] = __uint_as_float(v.w & 0xffff0000u);
    #pragma unroll
    for (int k = 0; k < 8; ++k) {
        int c = c0 + k;
        float mu = stats[c] * (1.f / NN);
        float var = stats[128 + c] * (1.f / NN) - mu * mu;
        o[k] = fmaxf((xv[k] - mu) * rsqrtf(var + BN_EPS) * gamma[c] + beta[c], 0.f);
    }
}

__global__ __launch_bounds__(256) void bn_apply_bf16(const bf16* __restrict__ x, const float* __restrict__ stats,
                                                     const float* __restrict__ gamma, const float* __restrict__ beta,
                                                     bf16* __restrict__ out) {
    int i = blockIdx.x * 256 + threadIdx.x;
    if (i >= NN * DF / 8) return;
    uint4 v = reinterpret_cast<const uint4*>(x)[i];
    float o[8];
    bn_core(v, (i * 8) & 127, stats, gamma, beta, o);
    uint4 w;
    unsigned short* wb = reinterpret_cast<unsigned short*>(&w);
    #pragma unroll
    for (int k = 0; k < 8; ++k) {
        union { bf16 b; unsigned short u; } t;
        t.b = __float2bfloat16(o[k]);
        wb[k] = t.u;
    }
    reinterpret_cast<uint4*>(out)[i] = w;
}

__global__ __launch_bounds__(256) void bn_apply_f32(const bf16* __restrict__ x, const float* __restrict__ stats,
                                                    const float* __restrict__ gamma, const float* __restrict__ beta,
                                                    float* __restrict__ out) {
    int i = blockIdx.x * 256 + threadIdx.x;
    if (i >= NN * DF / 8) return;
    uint4 v = reinterpret_cast<const uint4*>(x)[i];
    float o[8];
    bn_core(v, (i * 8) & 127, stats, gamma, beta, o);
    float4* op = reinterpret_cast<float4*>(out) + (size_t)i * 2;
    op[0] = make_float4(o[0], o[1], o[2], o[3]);
    op[1] = make_float4(o[4], o[5], o[6], o[7]);
}

extern "C" void kernel_launch(void* const* d_in, const int* in_sizes, int n_in,
                              void* d_out, int out_size, void* d_ws, size_t ws_size,
                              hipStream_t stream) {
    (void)in_sizes; (void)n_in; (void)out_size; (void)ws_size;
    const float* x   = (const float*)d_in[0];
    const int*   ei  = (const int*)d_in[1];
    const float* W1  = (const float*)d_in[2];
    const float* as1 = (const float*)d_in[3];
    const float* ad1 = (const float*)d_in[4];
    const float* b1  = (const float*)d_in[5];
    const float* g1  = (const float*)d_in[6];
    const float* be1 = (const float*)d_in[7];
    const float* W2  = (const float*)d_in[8];
    const float* as2 = (const float*)d_in[9];
    const float* ad2 = (const float*)d_in[10];
    const float* b2  = (const float*)d_in[11];
    const float* g2  = (const float*)d_in[12];
    const float* be2 = (const float*)d_in[13];
    float* out = (float*)d_out;

    char* ws = (char*)d_ws;
    size_t off = 0;
    auto alloc = [&](size_t bytes) -> void* {
        void* p = ws + off;
        off += (bytes + 255) & ~(size_t)255;
        return p;
    };
    bf16*   aggX    = (bf16*)alloc((size_t)NP * HD * 2);      // 51.25 MB
    bf16*   xb      = (bf16*)alloc((size_t)NP * DF * 2);      // 12.8 MB (padded)
    bf16*   Bt2a    = (bf16*)alloc((size_t)DF * HD * 2);      // 128 KB
    bf16*   Bt2b    = (bf16*)alloc((size_t)DF * HD * 2);
    float*  wsd     = (float*)alloc(2 * 1024 * 4);            // 8 KB
    float*  a_src   = (float*)alloc((size_t)NN * NH * 4);
    float*  a_dst   = (float*)alloc((size_t)NN * NH * 4);
    int*    row_ptr = (int*)alloc((size_t)(NN + 1) * 4);
    int*    bsum    = (int*)alloc(256 * 4);
    int*    colidx  = (int*)alloc((size_t)ET * 4);
    uint4*  rec     = (uint4*)alloc((size_t)ET * 16);         // 13.6 MB (deg>64 path only)
    bf16*   agg     = (bf16*)alloc((size_t)NN * DF * 2);      // 12.8 MB
    float*  stats   = (float*)alloc(256 * 4);
    // counts (padded 64B/dst, 3.2MB) + rank (3.4MB) aliased into agg (12.8MB;
    // agg first written by gemm_out, long after CSR build completes)
    int*    counts  = (int*)agg;
    int*    rank    = (int*)((char*)agg + ((size_t)NP << 6));
    // high-water ~89 MB (<= R1-proven 107.4 MB)

    const int NB = (NN + 255) / 256;        // 196
    const int EB2 = (ET / 2 + 255) / 256;   // 1661
    const int BNB = (NN * DF / 8 + 255) / 256;  // 3125

    // ---- prep + CSR build (single atomic pass) ----
    cvt_x_bf16<<<(NN * DF / 4 + 255) / 256, 256, 0, stream>>>(x, xb);
    make_wsd<<<8, 256, 0, stream>>>(W1, as1, ad1, W2, as2, ad2, wsd);
    cvt_bt2<<<(2 * DF * HD + 255) / 256, 256, 0, stream>>>(W1, W2, Bt2a, Bt2b);
    hipMemsetAsync(counts, 0, (size_t)NP << 6, stream);
    count_rank<<<EB2, 256, 0, stream>>>(ei, counts, rank);
    scan1<<<NB, 256, 0, stream>>>(counts, bsum);
    scan2<<<1, 256, 0, stream>>>(bsum, NB);
    scan3<<<NB, 256, 0, stream>>>(counts, bsum, row_ptr);
    fill_scatter<<<EB2, 256, 0, stream>>>(ei, rank, row_ptr, colidx);

    // ---- layer 1 ----
    xscore<<<NN / 4, 256, 0, stream>>>(xb, wsd, a_src, a_dst, stats);
    agg_fused<<<NN / 4, 256, 0, stream>>>(xb, a_src, a_dst, row_ptr, colidx, rec, aggX);
    gemm_out<<<NP / 64, 256, 0, stream>>>(aggX, Bt2a, b1, agg, stats, NN);
    bn_apply_bf16<<<BNB, 256, 0, stream>>>(agg, stats, g1, be1, xb);

    // ---- layer 2 ----
    xscore<<<NN / 4, 256, 0, stream>>>(xb, wsd + 1024, a_src, a_dst, stats);
    agg_fused<<<NN / 4, 256, 0, stream>>>(xb, a_src, a_dst, row_ptr, colidx, rec, aggX);
    gemm_out<<<NP / 64, 256, 0, stream>>>(aggX, Bt2b, b2, agg, stats, NN);
    bn_apply_f32<<<BNB, 256, 0, stream>>>(agg, stats, g2, be2, out);
}